// Round 2
// baseline (415.180 us; speedup 1.0000x reference)
//
#include <hip/hip_runtime.h>
#include <hip/hip_bf16.h>

#define Bsz 4
#define Ssz 2048
#define Esz 1024
#define Hsz 16
#define DHsz 64
#define QBLK 64
#define KBLK 64
#define LDK 72   // padded LDS row stride (bf16 elems): 144B, breaks 32-way conflicts

typedef __bf16 bf16x8 __attribute__((ext_vector_type(8)));
typedef __bf16 bf16x4 __attribute__((ext_vector_type(4)));
typedef float  f32x4  __attribute__((ext_vector_type(4)));

static __device__ __forceinline__ f32x4 mfma_16x16x32(bf16x8 a, bf16x8 b, f32x4 c) {
    return __builtin_amdgcn_mfma_f32_16x16x32_bf16(a, b, c, 0, 0, 0);
}

// ---------------- fused attention: out_ws[b][s][e] (bf16) ----------------
__global__ __launch_bounds__(256) void attn_kernel(
    const float* __restrict__ Q, const float* __restrict__ K,
    const float* __restrict__ V, const int* __restrict__ mask,
    const float* __restrict__ scale_p, const float* __restrict__ logC_p,
    __bf16* __restrict__ attn_out)
{
    __shared__ __bf16 k_hi[KBLK][LDK];
    __shared__ __bf16 k_lo[KBLK][LDK];
    __shared__ __bf16 v_t [DHsz][LDK];     // transposed: [dh][key]
    __shared__ __bf16 p_buf[4][16][LDK];   // per-wave P tile
    __shared__ float  maskf[KBLK];

    const int tid = threadIdx.x;
    const int l   = tid & 63;
    const int wid = tid >> 6;
    const int l15 = l & 15;
    const int l4  = l >> 4;

    const int qt = blockIdx.x;
    const int h  = blockIdx.y;
    const int b  = blockIdx.z;

    const float scale = scale_p[0];
    const float C  = __expf(logC_p[0]);
    const float su = scale * 0.125f;       // scale / sqrt(DH)

    // ---- load Q fragments once (hi/lo split), rows = qt*64 + wid*16 + l15
    const int qrow = qt * QBLK + wid * 16 + l15;
    const float* qp = Q + ((size_t)b * Ssz + qrow) * Esz + h * DHsz + l4 * 8;
    bf16x8 qhi[2], qlo[2];
#pragma unroll
    for (int c = 0; c < 2; ++c) {
        f32x4 v0 = *reinterpret_cast<const f32x4*>(qp + 32 * c);
        f32x4 v1 = *reinterpret_cast<const f32x4*>(qp + 32 * c + 4);
#pragma unroll
        for (int i = 0; i < 8; ++i) {
            float f = (i < 4) ? v0[i] : v1[i - 4];
            __bf16 hi = (__bf16)f;
            qhi[c][i] = hi;
            qlo[c][i] = (__bf16)(f - (float)hi);
        }
    }

    const f32x4 fzero = {0.f, 0.f, 0.f, 0.f};
    f32x4 oacc[4];
#pragma unroll
    for (int st = 0; st < 4; ++st) oacc[st] = fzero;
    float dsum[4] = {0.f, 0.f, 0.f, 0.f};

    for (int kt = 0; kt < Ssz / KBLK; ++kt) {
        const int kbase = kt * KBLK;
        __syncthreads();
        // ---- stage K (hi/lo) and V^T tiles, fp32 -> bf16
        for (int i = tid; i < KBLK * DHsz / 4; i += 256) {
            int kk = i >> 4;
            int d4 = (i & 15) * 4;
            size_t goff = ((size_t)b * Ssz + kbase + kk) * Esz + h * DHsz + d4;
            f32x4 kv = *reinterpret_cast<const f32x4*>(K + goff);
            f32x4 vv = *reinterpret_cast<const f32x4*>(V + goff);
            bf16x4 khiv, klov;
#pragma unroll
            for (int j = 0; j < 4; ++j) {
                __bf16 hi = (__bf16)kv[j];
                khiv[j] = hi;
                klov[j] = (__bf16)(kv[j] - (float)hi);
                v_t[d4 + j][kk] = (__bf16)vv[j];
            }
            *reinterpret_cast<bf16x4*>(&k_hi[kk][d4]) = khiv;
            *reinterpret_cast<bf16x4*>(&k_lo[kk][d4]) = klov;
        }
        if (tid < KBLK)
            maskf[tid] = mask[(size_t)b * Ssz + kbase + tid] ? 0.0f : 1.0f;
        __syncthreads();

        // ---- QK^T (hi/lo split: fp32-accurate) + masked exp(C*tanh(.))
#pragma unroll
        for (int st = 0; st < 4; ++st) {
            f32x4 sacc = fzero;
#pragma unroll
            for (int c = 0; c < 2; ++c) {
                bf16x8 bh = *reinterpret_cast<const bf16x8*>(&k_hi[st * 16 + l15][c * 32 + l4 * 8]);
                bf16x8 bl = *reinterpret_cast<const bf16x8*>(&k_lo[st * 16 + l15][c * 32 + l4 * 8]);
                sacc = mfma_16x16x32(qhi[c], bh, sacc);
                sacc = mfma_16x16x32(qlo[c], bh, sacc);
                sacc = mfma_16x16x32(qhi[c], bl, sacc);
            }
            float mk = maskf[st * 16 + l15];
#pragma unroll
            for (int r = 0; r < 4; ++r) {
                float u = sacc[r] * su;
                u = fminf(15.f, fmaxf(-15.f, u));
                float z = __expf(2.f * u);                 // e^{2u}
                float t = __fdividef(z - 1.f, z + 1.f);    // tanh(u)
                float p = __expf(C * t) * mk;              // bounded by e^{C}
                __bf16 pb = (__bf16)p;
                dsum[r] += (float)pb;
                p_buf[wid][l4 * 4 + r][st * 16 + l15] = pb;
            }
        }

        // ---- PV: O += P[16x64] * V[64x64]
#pragma unroll
        for (int c = 0; c < 2; ++c) {
            bf16x8 pa = *reinterpret_cast<const bf16x8*>(&p_buf[wid][l15][c * 32 + l4 * 8]);
#pragma unroll
            for (int st = 0; st < 4; ++st) {
                bf16x8 vb = *reinterpret_cast<const bf16x8*>(&v_t[st * 16 + l15][c * 32 + l4 * 8]);
                oacc[st] = mfma_16x16x32(pa, vb, oacc[st]);
            }
        }
    }

    // ---- reduce denominators across the 16 lanes sharing each row group
#pragma unroll
    for (int m = 1; m < 16; m <<= 1)
#pragma unroll
        for (int r = 0; r < 4; ++r)
            dsum[r] += __shfl_xor(dsum[r], m, 64);

#pragma unroll
    for (int st = 0; st < 4; ++st)
#pragma unroll
        for (int r = 0; r < 4; ++r) {
            float o = oacc[st][r] * __fdividef(1.f, dsum[r]);
            int row = qt * QBLK + wid * 16 + l4 * 4 + r;
            attn_out[((size_t)b * Ssz + row) * Esz + h * DHsz + st * 16 + l15] = (__bf16)o;
        }
}

// ---------------- out = X(bf16)[8192,1024] @ W^T(fp32->bf16), fp32 out ----
__global__ __launch_bounds__(256) void out_gemm(
    const __bf16* __restrict__ X, const float* __restrict__ W,
    float* __restrict__ out)
{
    __shared__ __bf16 xs[64][LDK];
    __shared__ __bf16 wt[64][LDK];

    const int tid = threadIdx.x;
    const int l   = tid & 63;
    const int wid = tid >> 6;
    const int l15 = l & 15;
    const int l4  = l >> 4;
    const int mbase = blockIdx.x * 64;
    const int nbase = blockIdx.y * 64;

    const f32x4 fzero = {0.f, 0.f, 0.f, 0.f};
    f32x4 acc[4];
#pragma unroll
    for (int st = 0; st < 4; ++st) acc[st] = fzero;

    for (int kt = 0; kt < Esz / 64; ++kt) {
        const int kbase = kt * 64;
        __syncthreads();
        for (int i = tid; i < 64 * 8; i += 256) {          // X tile, vec8 bf16
            int r = i >> 3, c8 = (i & 7) * 8;
            *reinterpret_cast<bf16x8*>(&xs[r][c8]) =
                *reinterpret_cast<const bf16x8*>(X + (size_t)(mbase + r) * Esz + kbase + c8);
        }
        for (int i = tid; i < 64 * 16; i += 256) {         // W tile, fp32->bf16
            int r = i >> 4, c4 = (i & 15) * 4;
            f32x4 wv = *reinterpret_cast<const f32x4*>(W + (size_t)(nbase + r) * Esz + kbase + c4);
            bf16x4 wb;
#pragma unroll
            for (int j = 0; j < 4; ++j) wb[j] = (__bf16)wv[j];
            *reinterpret_cast<bf16x4*>(&wt[r][c4]) = wb;
        }
        __syncthreads();

        bf16x8 a0 = *reinterpret_cast<const bf16x8*>(&xs[wid * 16 + l15][l4 * 8]);
        bf16x8 a1 = *reinterpret_cast<const bf16x8*>(&xs[wid * 16 + l15][32 + l4 * 8]);
#pragma unroll
        for (int st = 0; st < 4; ++st) {
            bf16x8 b0 = *reinterpret_cast<const bf16x8*>(&wt[st * 16 + l15][l4 * 8]);
            bf16x8 b1 = *reinterpret_cast<const bf16x8*>(&wt[st * 16 + l15][32 + l4 * 8]);
            acc[st] = mfma_16x16x32(a0, b0, acc[st]);
            acc[st] = mfma_16x16x32(a1, b1, acc[st]);
        }
    }

#pragma unroll
    for (int st = 0; st < 4; ++st)
#pragma unroll
        for (int r = 0; r < 4; ++r)
            out[(size_t)(mbase + wid * 16 + l4 * 4 + r) * Esz + nbase + st * 16 + l15] = acc[st][r];
}

extern "C" void kernel_launch(void* const* d_in, const int* in_sizes, int n_in,
                              void* d_out, int out_size, void* d_ws, size_t ws_size,
                              hipStream_t stream) {
    const float* Q     = (const float*)d_in[0];
    const float* K     = (const float*)d_in[1];
    const float* V     = (const float*)d_in[2];
    const int*   mask  = (const int*)d_in[3];
    const float* W     = (const float*)d_in[4];
    const float* scale = (const float*)d_in[5];
    const float* logC  = (const float*)d_in[6];

    __bf16* attn = (__bf16*)d_ws;            // B*S*E bf16 = 16 MiB scratch
    float*  out  = (float*)d_out;

    attn_kernel<<<dim3(Ssz / QBLK, Hsz, Bsz), 256, 0, stream>>>(
        Q, K, V, mask, scale, logC, attn);
    out_gemm<<<dim3((Bsz * Ssz) / 64, Esz / 64), 256, 0, stream>>>(attn, W, out);
}

// Round 3
// 401.537 us; speedup vs baseline: 1.0340x; 1.0340x over previous
//
#include <hip/hip_runtime.h>
#include <hip/hip_bf16.h>

#define Bsz 4
#define Ssz 2048
#define Esz 1024
#define Hsz 16
#define DHsz 64
#define QBLK 64
#define KBLK 64

typedef __bf16 bf16x8 __attribute__((ext_vector_type(8)));
typedef __bf16 bf16x4 __attribute__((ext_vector_type(4)));
typedef float  f32x4  __attribute__((ext_vector_type(4)));

static __device__ __forceinline__ f32x4 mfma16(bf16x8 a, bf16x8 b, f32x4 c) {
    return __builtin_amdgcn_mfma_f32_16x16x32_bf16(a, b, c, 0, 0, 0);
}

// Swizzled LDS addressing: tiles have linear 128B rows (64 bf16), and the
// 16B slot within a row is XOR'd with (row&7). All reads/writes use the
// same involution => conflict-free for row-sliced b128 fragment reads.
static __device__ __forceinline__ char* swz(char* base, int row, int colByte) {
    return base + row * 128 + (colByte ^ ((row & 7) << 4));
}

// ---------------- fused attention: attn_out[b][s][e] (bf16) ----------------
__global__ __launch_bounds__(256) void attn_kernel(
    const float* __restrict__ Q, const float* __restrict__ K,
    const float* __restrict__ V, const int* __restrict__ mask,
    const float* __restrict__ scale_p, const float* __restrict__ logC_p,
    __bf16* __restrict__ attn_out)
{
    __shared__ __bf16 k_hi[KBLK * 64];
    __shared__ __bf16 k_lo[KBLK * 64];
    __shared__ __bf16 v_t [DHsz * 64];     // transposed: [dh][key]
    __shared__ __bf16 p_s [4 * 16 * 64];   // per-wave P^ [query][key]
    __shared__ float  maskf[KBLK];         // 0 or e^C

    const int tid = threadIdx.x;
    const int l   = tid & 63;
    const int wid = tid >> 6;
    const int l15 = l & 15;
    const int l4  = l >> 4;

    const int qt = blockIdx.x;
    const int h  = blockIdx.y;
    const int b  = blockIdx.z;

    const float scale = scale_p[0];
    const float C    = __expf(logC_p[0]);
    const float eC   = __expf(C);
    const float k1f  = scale * 0.125f * 2.0f;   // z = e^{2u}, u = s*scale/8
    const float kneg = -2.0f * C;               // p = eC * e^{kneg/(z+1)}

    char* khb = (char*)k_hi;
    char* klb = (char*)k_lo;
    char* vtb = (char*)v_t;
    char* pb  = (char*)p_s + wid * (16 * 128);

    // ---- Q fragments (hi/lo split), used as MFMA B operand; query = wid*16+l15
    const int qrow = qt * QBLK + wid * 16 + l15;
    const float* qp = Q + ((size_t)b * Ssz + qrow) * Esz + h * DHsz + l4 * 8;
    bf16x8 qhi[2], qlo[2];
#pragma unroll
    for (int c = 0; c < 2; ++c) {
        f32x4 v0 = *reinterpret_cast<const f32x4*>(qp + 32 * c);
        f32x4 v1 = *reinterpret_cast<const f32x4*>(qp + 32 * c + 4);
#pragma unroll
        for (int i = 0; i < 8; ++i) {
            float f = (i < 4) ? v0[i] : v1[i - 4];
            __bf16 hi = (__bf16)f;
            qhi[c][i] = hi;
            qlo[c][i] = (__bf16)(f - (float)hi);
        }
    }

    const f32x4 fzero = {0.f, 0.f, 0.f, 0.f};
    f32x4 oacc[4];
#pragma unroll
    for (int st = 0; st < 4; ++st) oacc[st] = fzero;
    float dsum = 0.0f;

    for (int kt = 0; kt < Ssz / KBLK; ++kt) {
        const int kbase = kt * KBLK;
        __syncthreads();

        // ---- stage K (hi/lo): lane covers (key = idx>>4, d4 = (idx&15)*4)
#pragma unroll
        for (int it = 0; it < 4; ++it) {
            int idx = it * 256 + tid;
            int key = idx >> 4;
            int d4  = (idx & 15) * 4;
            f32x4 kv = *reinterpret_cast<const f32x4*>(
                K + ((size_t)b * Ssz + kbase + key) * Esz + h * DHsz + d4);
            bf16x4 khiv, klov;
#pragma unroll
            for (int j = 0; j < 4; ++j) {
                __bf16 hi = (__bf16)kv[j];
                khiv[j] = hi;
                klov[j] = (__bf16)(kv[j] - (float)hi);
            }
            *reinterpret_cast<bf16x4*>(swz(khb, key, d4 * 2)) = khiv;
            *reinterpret_cast<bf16x4*>(swz(klb, key, d4 * 2)) = klov;
        }

        // ---- stage V^T: lane owns key=l (full 64B line), wave owns 16 dh rows.
        // Each scalar-write instr has a uniform row across the wave => no conflicts.
        {
            const float* vrow = V + ((size_t)b * Ssz + kbase + l) * Esz + h * DHsz + wid * 16;
#pragma unroll
            for (int q = 0; q < 4; ++q) {
                f32x4 vv = *reinterpret_cast<const f32x4*>(vrow + q * 4);
#pragma unroll
                for (int j = 0; j < 4; ++j) {
                    int row = wid * 16 + q * 4 + j;
                    *reinterpret_cast<__bf16*>(swz(vtb, row, l * 2)) = (__bf16)vv[j];
                }
            }
        }
        if (tid < KBLK)
            maskf[tid] = mask[(size_t)b * Ssz + kbase + tid] ? 0.0f : eC;
        __syncthreads();

        // ---- swapped QK^T: P[key][query]; lane holds keys st*16+l4*4+r, query l15
#pragma unroll
        for (int st = 0; st < 4; ++st) {
            f32x4 sacc = fzero;
#pragma unroll
            for (int c = 0; c < 2; ++c) {
                bf16x8 ah = *reinterpret_cast<const bf16x8*>(swz(khb, st * 16 + l15, c * 64 + l4 * 16));
                bf16x8 al = *reinterpret_cast<const bf16x8*>(swz(klb, st * 16 + l15, c * 64 + l4 * 16));
                sacc = mfma16(ah, qhi[c], sacc);
                sacc = mfma16(ah, qlo[c], sacc);
                sacc = mfma16(al, qhi[c], sacc);
            }
            f32x4 mkv = *reinterpret_cast<const f32x4*>(&maskf[st * 16 + l4 * 4]);
            bf16x4 pv4;
            float loc = 0.0f;
#pragma unroll
            for (int r = 0; r < 4; ++r) {
                float z = __expf(sacc[r] * k1f);                    // e^{2u}, inf-safe
                float inv = __fdividef(1.0f, z + 1.0f);
                float p = __expf(kneg * inv) * mkv[r];              // mk in {0, e^C}
                pv4[r] = (__bf16)p;
                loc += p;
            }
            dsum += loc;
            *reinterpret_cast<bf16x4*>(swz(pb, l15, (st * 16 + l4 * 4) * 2)) = pv4;
        }

        // ---- PV: O[query][dh] += P[16x64] * V^T
#pragma unroll
        for (int c = 0; c < 2; ++c) {
            bf16x8 pa = *reinterpret_cast<const bf16x8*>(swz(pb, l15, c * 64 + l4 * 16));
#pragma unroll
            for (int st = 0; st < 4; ++st) {
                bf16x8 vb = *reinterpret_cast<const bf16x8*>(swz(vtb, st * 16 + l15, c * 64 + l4 * 16));
                oacc[st] = mfma16(pa, vb, oacc[st]);
            }
        }
    }

    // ---- finalize: denominator for query l15, then redistribute to output rows
    dsum += __shfl_xor(dsum, 16, 64);
    dsum += __shfl_xor(dsum, 32, 64);
    float dd[4];
#pragma unroll
    for (int r = 0; r < 4; ++r)
        dd[r] = __shfl(dsum, l4 * 4 + r, 64);   // lane q holds query q's sum

#pragma unroll
    for (int st = 0; st < 4; ++st)
#pragma unroll
        for (int r = 0; r < 4; ++r) {
            float o = oacc[st][r] * __fdividef(1.0f, dd[r]);
            int row = qt * QBLK + wid * 16 + l4 * 4 + r;
            attn_out[((size_t)b * Ssz + row) * Esz + h * DHsz + st * 16 + l15] = (__bf16)o;
        }
}

// ---------------- out = X(bf16)[8192,1024] @ W^T(fp32->bf16), fp32 out ----
__global__ __launch_bounds__(256) void out_gemm(
    const __bf16* __restrict__ X, const float* __restrict__ W,
    float* __restrict__ out)
{
    __shared__ __bf16 xs[64 * 64];
    __shared__ __bf16 wt[64 * 64];
    char* xsb = (char*)xs;
    char* wtb = (char*)wt;

    const int tid = threadIdx.x;
    const int l   = tid & 63;
    const int wid = tid >> 6;
    const int l15 = l & 15;
    const int l4  = l >> 4;
    const int mbase = blockIdx.x * 64;
    const int nbase = blockIdx.y * 64;

    const f32x4 fzero = {0.f, 0.f, 0.f, 0.f};
    f32x4 acc[4];
#pragma unroll
    for (int st = 0; st < 4; ++st) acc[st] = fzero;

    for (int kt = 0; kt < Esz / 64; ++kt) {
        const int kbase = kt * 64;
        __syncthreads();
        for (int i = tid; i < 64 * 8; i += 256) {          // X tile, vec8 bf16
            int r = i >> 3, c8 = i & 7;
            *reinterpret_cast<bf16x8*>(swz(xsb, r, c8 * 16)) =
                *reinterpret_cast<const bf16x8*>(X + (size_t)(mbase + r) * Esz + kbase + c8 * 8);
        }
        for (int i = tid; i < 64 * 16; i += 256) {         // W tile, fp32->bf16
            int r = i >> 4, c4 = i & 15;
            f32x4 wv = *reinterpret_cast<const f32x4*>(W + (size_t)(nbase + r) * Esz + kbase + c4 * 4);
            bf16x4 wb;
#pragma unroll
            for (int j = 0; j < 4; ++j) wb[j] = (__bf16)wv[j];
            *reinterpret_cast<bf16x4*>(swz(wtb, r, c4 * 8)) = wb;
        }
        __syncthreads();

        bf16x8 a0 = *reinterpret_cast<const bf16x8*>(swz(xsb, wid * 16 + l15, l4 * 16));
        bf16x8 a1 = *reinterpret_cast<const bf16x8*>(swz(xsb, wid * 16 + l15, 64 + l4 * 16));
#pragma unroll
        for (int st = 0; st < 4; ++st) {
            bf16x8 b0 = *reinterpret_cast<const bf16x8*>(swz(wtb, st * 16 + l15, l4 * 16));
            bf16x8 b1 = *reinterpret_cast<const bf16x8*>(swz(wtb, st * 16 + l15, 64 + l4 * 16));
            acc[st] = mfma16(a0, b0, acc[st]);
            acc[st] = mfma16(a1, b1, acc[st]);
        }
    }

#pragma unroll
    for (int st = 0; st < 4; ++st)
#pragma unroll
        for (int r = 0; r < 4; ++r)
            out[(size_t)(mbase + wid * 16 + l4 * 4 + r) * Esz + nbase + st * 16 + l15] = acc[st][r];
}

extern "C" void kernel_launch(void* const* d_in, const int* in_sizes, int n_in,
                              void* d_out, int out_size, void* d_ws, size_t ws_size,
                              hipStream_t stream) {
    const float* Q     = (const float*)d_in[0];
    const float* K     = (const float*)d_in[1];
    const float* V     = (const float*)d_in[2];
    const int*   mask  = (const int*)d_in[3];
    const float* W     = (const float*)d_in[4];
    const float* scale = (const float*)d_in[5];
    const float* logC  = (const float*)d_in[6];

    __bf16* attn = (__bf16*)d_ws;            // B*S*E bf16 = 16 MiB scratch
    float*  out  = (float*)d_out;

    attn_kernel<<<dim3(Ssz / QBLK, Hsz, Bsz), 256, 0, stream>>>(
        Q, K, V, mask, scale, logC, attn);
    out_gemm<<<dim3((Bsz * Ssz) / 64, Esz / 64), 256, 0, stream>>>(attn, W, out);
}

// Round 4
// 247.981 us; speedup vs baseline: 1.6742x; 1.6192x over previous
//
#include <hip/hip_runtime.h>
#include <hip/hip_bf16.h>

#define Bsz 4
#define Ssz 2048
#define Esz 1024
#define Hsz 16
#define DHsz 64

// KV tile image: khi 8KB | klo 8KB | vt 8KB | mask 256B  (per (b,h,kt64))
#define TILE_B 24832
#define NKT    (Ssz / 64)               // 32 key tiles
#define KVT_BYTES ((size_t)Bsz * Hsz * NKT * TILE_B)   // 50,855,936
#define WT_OFF  50855936                // 256 W tiles x 8KB = 2MB
#define X_OFF   52953088                // bf16 X, 16MB

typedef __bf16 bf16x8 __attribute__((ext_vector_type(8)));
typedef __bf16 bf16x4 __attribute__((ext_vector_type(4)));
typedef float  f32x4  __attribute__((ext_vector_type(4)));

static __device__ __forceinline__ f32x4 mfma16(bf16x8 a, bf16x8 b, f32x4 c) {
    return __builtin_amdgcn_mfma_f32_16x16x32_bf16(a, b, c, 0, 0, 0);
}

// Swizzled tile addressing: linear 128B rows, 16B slot XOR'd with (row&7).
static __device__ __forceinline__ char* swz(char* base, int row, int colByte) {
    return base + row * 128 + (colByte ^ ((row & 7) << 4));
}
static __device__ __forceinline__ const char* swzc(const char* base, int row, int colByte) {
    return base + row * 128 + (colByte ^ ((row & 7) << 4));
}

typedef const unsigned int __attribute__((address_space(1))) as1_u32;
typedef unsigned int __attribute__((address_space(3))) as3_u32;
static __device__ __forceinline__ void gl_lds16(const void* g, void* l) {
    __builtin_amdgcn_global_load_lds((as1_u32*)g, (as3_u32*)l, 16, 0, 0);
}
static __device__ __forceinline__ void gl_lds4(const void* g, void* l) {
    __builtin_amdgcn_global_load_lds((as1_u32*)g, (as3_u32*)l, 4, 0, 0);
}

static __device__ __forceinline__ float fexp2(float x) {
#if __has_builtin(__builtin_amdgcn_exp2f)
    return __builtin_amdgcn_exp2f(x);
#else
    return __expf(x * 0.6931471805599453f);
#endif
}
static __device__ __forceinline__ float frcp(float x) {
#if __has_builtin(__builtin_amdgcn_rcpf)
    return __builtin_amdgcn_rcpf(x);
#else
    return __fdividef(1.0f, x);
#endif
}

// ---------- prepass: K->hi/lo bf16, V->V^T bf16, mask->f32; swizzled tiles ----------
__global__ __launch_bounds__(256) void prep_kv(
    const float* __restrict__ K, const float* __restrict__ V,
    const int* __restrict__ mask, char* __restrict__ KVt)
{
    const int kt = blockIdx.x, h = blockIdx.y, b = blockIdx.z;
    char* tile = KVt + (size_t)((b * Hsz + h) * NKT + kt) * TILE_B;
    const int tid = threadIdx.x;

    {   // K hi/lo: thread -> row kk, d-segment seg*16
        const int kk = tid >> 2, seg = tid & 3;
        const float* kp = K + ((size_t)b * Ssz + kt * 64 + kk) * Esz + h * DHsz + seg * 16;
        bf16x8 hv[2], lv[2];
#pragma unroll
        for (int hf = 0; hf < 2; ++hf) {
            f32x4 a = *(const f32x4*)(kp + hf * 8);
            f32x4 c = *(const f32x4*)(kp + hf * 8 + 4);
#pragma unroll
            for (int i = 0; i < 8; ++i) {
                float f = (i < 4) ? a[i] : c[i - 4];
                __bf16 hi = (__bf16)f;
                hv[hf][i] = hi;
                lv[hf][i] = (__bf16)(f - (float)hi);
            }
        }
        const int x = (kk & 7) << 4;
        *(bf16x8*)(tile + kk * 128 + ((seg * 32) ^ x))           = hv[0];
        *(bf16x8*)(tile + kk * 128 + ((seg * 32 + 16) ^ x))      = hv[1];
        *(bf16x8*)(tile + 8192 + kk * 128 + ((seg * 32) ^ x))    = lv[0];
        *(bf16x8*)(tile + 8192 + kk * 128 + ((seg * 32 + 16) ^ x)) = lv[1];
    }
    {   // V^T: thread -> dh row d, key segment ks*16
        const int d = tid & 63, ks = tid >> 6;
        const float* vp = V + ((size_t)b * Ssz + kt * 64 + ks * 16) * Esz + h * DHsz + d;
        bf16x8 t[2];
#pragma unroll
        for (int j = 0; j < 16; ++j)
            t[j >> 3][j & 7] = (__bf16)vp[(size_t)j * Esz];
        const int x = (d & 7) << 4;
        *(bf16x8*)(tile + 16384 + d * 128 + ((ks * 32) ^ x))      = t[0];
        *(bf16x8*)(tile + 16384 + d * 128 + ((ks * 32 + 16) ^ x)) = t[1];
    }
    if (tid < 64)
        *(float*)(tile + 24576 + tid * 4) =
            mask[(size_t)b * Ssz + kt * 64 + tid] ? 0.0f : 1.0f;
}

__global__ __launch_bounds__(256) void prep_w(
    const float* __restrict__ W, char* __restrict__ Wt)
{
    const int kt = blockIdx.x, nt = blockIdx.y;
    char* tile = Wt + (size_t)(nt * 16 + kt) * 8192;
    const int n = threadIdx.x >> 2, seg = threadIdx.x & 3;
    const float* wp = W + (size_t)(nt * 64 + n) * Esz + kt * 64 + seg * 16;
    bf16x8 t[2];
#pragma unroll
    for (int hf = 0; hf < 2; ++hf) {
        f32x4 a = *(const f32x4*)(wp + hf * 8);
        f32x4 c = *(const f32x4*)(wp + hf * 8 + 4);
#pragma unroll
        for (int i = 0; i < 8; ++i) t[hf][i] = (__bf16)((i < 4) ? a[i] : c[i - 4]);
    }
    const int x = (n & 7) << 4;
    *(bf16x8*)(tile + n * 128 + ((seg * 32) ^ x))      = t[0];
    *(bf16x8*)(tile + n * 128 + ((seg * 32 + 16) ^ x)) = t[1];
}

// ---------- fused attention: 128 queries/block, dbuf global_load_lds ----------
static __device__ __forceinline__ void stage(char* buf, const char* tile, int wid, int lane) {
#pragma unroll
    for (int i = 0; i < 6; ++i) {
        const int c = wid * 6 + i;
        gl_lds16(tile + c * 1024 + lane * 16, buf + c * 1024);
    }
    if (wid == 0)
        gl_lds4(tile + 24576 + lane * 4, buf + 24576);
}

__global__ __launch_bounds__(256, 2) void attn_kernel(
    const char* __restrict__ KVt, const float* __restrict__ Q,
    const float* __restrict__ scale_p, const float* __restrict__ logC_p,
    __bf16* __restrict__ X)
{
    __shared__ __align__(16) char   kvb[2][TILE_B];
    __shared__ __align__(16) __bf16 p_s[4][32 * 64];

    const int tid = threadIdx.x;
    const int l   = tid & 63;
    const int wid = tid >> 6;
    const int l15 = l & 15;
    const int l4  = l >> 4;
    const int qt = blockIdx.x, h = blockIdx.y, b = blockIdx.z;

    const float LOG2E = 1.4426950408889634f;
    const float scale = scale_p[0];
    const float C     = __expf(logC_p[0]);
    const float k1l2  = scale * 0.25f * LOG2E;   // z = 2^(s*k1l2) = e^{2u}
    const float Cl2   = C * LOG2E;
    const float negl2 = -2.0f * C * LOG2E;       // p = 2^(Cl2 + negl2/(z+1))

    const char* tiles = KVt + (size_t)((b * Hsz + h) * NKT) * TILE_B;

    // Q fragments (hi/lo), 2 groups of 16 queries per wave
    bf16x8 qhi[2][2], qlo[2][2];
#pragma unroll
    for (int g = 0; g < 2; ++g) {
        const int qrow = qt * 128 + wid * 32 + g * 16 + l15;
        const float* qp = Q + ((size_t)b * Ssz + qrow) * Esz + h * DHsz + l4 * 8;
#pragma unroll
        for (int c = 0; c < 2; ++c) {
            f32x4 v0 = *(const f32x4*)(qp + 32 * c);
            f32x4 v1 = *(const f32x4*)(qp + 32 * c + 4);
#pragma unroll
            for (int i = 0; i < 8; ++i) {
                float f = (i < 4) ? v0[i] : v1[i - 4];
                __bf16 hi = (__bf16)f;
                qhi[g][c][i] = hi;
                qlo[g][c][i] = (__bf16)(f - (float)hi);
            }
        }
    }

    const f32x4 fzero = {0.f, 0.f, 0.f, 0.f};
    f32x4 oacc[2][4];
#pragma unroll
    for (int g = 0; g < 2; ++g)
#pragma unroll
        for (int st = 0; st < 4; ++st) oacc[g][st] = fzero;
    float dsum[2] = {0.f, 0.f};
    char* pb = (char*)&p_s[wid][0];

    stage(kvb[0], tiles, wid, l);
    int cur = 0;
    for (int kt = 0; kt < NKT; ++kt) {
        __syncthreads();                      // drains vmcnt: buf[cur] ready; prev compute done
        if (kt < NKT - 1)
            stage(kvb[cur ^ 1], tiles + (size_t)(kt + 1) * TILE_B, wid, l);

        char* khb = kvb[cur];
        char* klb = khb + 8192;
        char* vtb = khb + 16384;
        const float* mkb = (const float*)(khb + 24576);

        // ---- QK^T (K-frags read once, feed both query groups) + softmax
#pragma unroll
        for (int st = 0; st < 4; ++st) {
            bf16x8 ah[2], al[2];
#pragma unroll
            for (int c = 0; c < 2; ++c) {
                ah[c] = *(const bf16x8*)swz(khb, st * 16 + l15, c * 64 + l4 * 16);
                al[c] = *(const bf16x8*)swz(klb, st * 16 + l15, c * 64 + l4 * 16);
            }
            f32x4 mkv = *(const f32x4*)(mkb + st * 16 + l4 * 4);
#pragma unroll
            for (int g = 0; g < 2; ++g) {
                f32x4 sacc = fzero;
#pragma unroll
                for (int c = 0; c < 2; ++c) {
                    sacc = mfma16(ah[c], qhi[g][c], sacc);
                    sacc = mfma16(ah[c], qlo[g][c], sacc);
                    sacc = mfma16(al[c], qhi[g][c], sacc);
                }
                bf16x4 pv4;
                float loc = 0.0f;
#pragma unroll
                for (int r = 0; r < 4; ++r) {
                    float z = fexp2(sacc[r] * k1l2);
                    float inv = frcp(z + 1.0f);
                    float p = fexp2(fmaf(negl2, inv, Cl2)) * mkv[r];
                    pv4[r] = (__bf16)p;
                    loc += p;
                }
                dsum[g] += loc;
                *(bf16x4*)swz(pb, g * 16 + l15, (st * 16 + l4 * 4) * 2) = pv4;
            }
        }

        // ---- PV: V-frags read once, feed both groups
#pragma unroll
        for (int c = 0; c < 2; ++c) {
            bf16x8 pa0 = *(const bf16x8*)swz(pb, l15,      c * 64 + l4 * 16);
            bf16x8 pa1 = *(const bf16x8*)swz(pb, 16 + l15, c * 64 + l4 * 16);
#pragma unroll
            for (int st = 0; st < 4; ++st) {
                bf16x8 vb = *(const bf16x8*)swz(vtb, st * 16 + l15, c * 64 + l4 * 16);
                oacc[0][st] = mfma16(pa0, vb, oacc[0][st]);
                oacc[1][st] = mfma16(pa1, vb, oacc[1][st]);
            }
        }
        cur ^= 1;
    }

    // ---- epilogue: denominators + store
#pragma unroll
    for (int g = 0; g < 2; ++g) {
        dsum[g] += __shfl_xor(dsum[g], 16, 64);
        dsum[g] += __shfl_xor(dsum[g], 32, 64);
    }
#pragma unroll
    for (int g = 0; g < 2; ++g) {
        float dd[4];
#pragma unroll
        for (int r = 0; r < 4; ++r)
            dd[r] = frcp(__shfl(dsum[g], l4 * 4 + r, 64));
#pragma unroll
        for (int st = 0; st < 4; ++st)
#pragma unroll
            for (int r = 0; r < 4; ++r) {
                int row = qt * 128 + wid * 32 + g * 16 + l4 * 4 + r;
                X[((size_t)b * Ssz + row) * Esz + h * DHsz + st * 16 + l15] =
                    (__bf16)(oacc[g][st][r] * dd[r]);
            }
    }
}

// ---------- out = X(bf16) @ W^T (prepped bf16 tiles), fp32 out ----------
__global__ __launch_bounds__(256) void out_gemm(
    const __bf16* __restrict__ X, const char* __restrict__ Wt,
    float* __restrict__ out)
{
    __shared__ __align__(16) __bf16 xs[4096];
    __shared__ __align__(16) __bf16 wt[4096];
    char* xsb = (char*)xs;
    char* wtb = (char*)wt;

    const int tid = threadIdx.x;
    const int l   = tid & 63;
    const int wid = tid >> 6;
    const int l15 = l & 15;
    const int l4  = l >> 4;
    const int mbase = blockIdx.x * 64;
    const int nt    = blockIdx.y;

    const f32x4 fzero = {0.f, 0.f, 0.f, 0.f};
    f32x4 acc[4];
#pragma unroll
    for (int st = 0; st < 4; ++st) acc[st] = fzero;

    for (int kt = 0; kt < Esz / 64; ++kt) {
        __syncthreads();
        // W tile: direct global->LDS (pre-swizzled image)
        {
            const char* wtile = Wt + (size_t)(nt * 16 + kt) * 8192;
#pragma unroll
            for (int i = 0; i < 2; ++i) {
                const int c = wid * 2 + i;
                gl_lds16(wtile + c * 1024 + l * 16, wtb + c * 1024);
            }
        }
        // X tile: reg path with swizzled writes
        for (int i = tid; i < 64 * 8; i += 256) {
            int r = i >> 3, c8 = i & 7;
            *(bf16x8*)swz(xsb, r, c8 * 16) =
                *(const bf16x8*)(X + (size_t)(mbase + r) * Esz + kt * 64 + c8 * 8);
        }
        __syncthreads();

        bf16x8 a0 = *(const bf16x8*)swz(xsb, wid * 16 + l15, l4 * 16);
        bf16x8 a1 = *(const bf16x8*)swz(xsb, wid * 16 + l15, 64 + l4 * 16);
#pragma unroll
        for (int st = 0; st < 4; ++st) {
            bf16x8 b0 = *(const bf16x8*)swz(wtb, st * 16 + l15, l4 * 16);
            bf16x8 b1 = *(const bf16x8*)swz(wtb, st * 16 + l15, 64 + l4 * 16);
            acc[st] = mfma16(a0, b0, acc[st]);
            acc[st] = mfma16(a1, b1, acc[st]);
        }
    }

#pragma unroll
    for (int st = 0; st < 4; ++st)
#pragma unroll
        for (int r = 0; r < 4; ++r)
            out[(size_t)(mbase + wid * 16 + l4 * 4 + r) * Esz + nt * 64 + st * 16 + l15] = acc[st][r];
}

extern "C" void kernel_launch(void* const* d_in, const int* in_sizes, int n_in,
                              void* d_out, int out_size, void* d_ws, size_t ws_size,
                              hipStream_t stream) {
    const float* Q     = (const float*)d_in[0];
    const float* K     = (const float*)d_in[1];
    const float* V     = (const float*)d_in[2];
    const int*   mask  = (const int*)d_in[3];
    const float* W     = (const float*)d_in[4];
    const float* scale = (const float*)d_in[5];
    const float* logC  = (const float*)d_in[6];

    char*   ws  = (char*)d_ws;          // needs ~66.5 MB scratch
    char*   KVt = ws;
    char*   Wt  = ws + WT_OFF;
    __bf16* X   = (__bf16*)(ws + X_OFF);
    float*  out = (float*)d_out;

    prep_kv<<<dim3(NKT, Hsz, Bsz), 256, 0, stream>>>(K, V, mask, KVt);
    prep_w<<<dim3(16, 16), 256, 0, stream>>>(W, Wt);
    attn_kernel<<<dim3(Ssz / 128, Hsz, Bsz), 256, 0, stream>>>(KVt, Q, scale, logC, X);
    out_gemm<<<dim3((Bsz * Ssz) / 64, Esz / 64), 256, 0, stream>>>(X, Wt, out);
}

// Round 5
// 202.259 us; speedup vs baseline: 2.0527x; 1.2261x over previous
//
#include <hip/hip_runtime.h>
#include <hip/hip_bf16.h>

#define Bsz 4
#define Ssz 2048
#define Esz 1024
#define Hsz 16
#define DHsz 64

// KV tile image (fp16): k 8KB | vt 8KB | mask(f32) 256B   per (b,h,kt64)
#define TILE_B 16640
#define NKT    (Ssz / 64)                    // 32 key tiles
#define KVT_BYTES ((size_t)Bsz * Hsz * NKT * TILE_B)   // 34,078,720
#define WT_OFF  34078720                     // 256 W tiles x 8KB = 2MB
#define X_OFF   36175872                     // fp16 X, 16MB

typedef _Float16 f16x8 __attribute__((ext_vector_type(8)));
typedef _Float16 f16x4 __attribute__((ext_vector_type(4)));
typedef float    f32x4 __attribute__((ext_vector_type(4)));

static __device__ __forceinline__ f32x4 mfma16h(f16x8 a, f16x8 b, f32x4 c) {
    return __builtin_amdgcn_mfma_f32_16x16x32_f16(a, b, c, 0, 0, 0);
}

// Swizzled tile addressing: linear 128B rows, 16B slot XOR'd with (row&7).
static __device__ __forceinline__ char* swz(char* base, int row, int colByte) {
    return base + row * 128 + (colByte ^ ((row & 7) << 4));
}

typedef const unsigned int __attribute__((address_space(1))) as1_u32;
typedef unsigned int __attribute__((address_space(3))) as3_u32;
static __device__ __forceinline__ void gl_lds16(const void* g, void* l) {
    __builtin_amdgcn_global_load_lds((as1_u32*)g, (as3_u32*)l, 16, 0, 0);
}
static __device__ __forceinline__ void gl_lds4(const void* g, void* l) {
    __builtin_amdgcn_global_load_lds((as1_u32*)g, (as3_u32*)l, 4, 0, 0);
}

static __device__ __forceinline__ float fexp2(float x) {
#if __has_builtin(__builtin_amdgcn_exp2f)
    return __builtin_amdgcn_exp2f(x);
#else
    return __expf(x * 0.6931471805599453f);
#endif
}
static __device__ __forceinline__ float frcp(float x) {
#if __has_builtin(__builtin_amdgcn_rcpf)
    return __builtin_amdgcn_rcpf(x);
#else
    return __fdividef(1.0f, x);
#endif
}

// ---------- prepass: K->fp16, V->V^T fp16, mask->f32; swizzled tile images ----------
__global__ __launch_bounds__(256) void prep_kv(
    const float* __restrict__ K, const float* __restrict__ V,
    const int* __restrict__ mask, char* __restrict__ KVt)
{
    const int kt = blockIdx.x, h = blockIdx.y, b = blockIdx.z;
    char* tile = KVt + (size_t)((b * Hsz + h) * NKT + kt) * TILE_B;
    const int tid = threadIdx.x;

    {   // K: thread -> row kk, d-segment seg*16
        const int kk = tid >> 2, seg = tid & 3;
        const float* kp = K + ((size_t)b * Ssz + kt * 64 + kk) * Esz + h * DHsz + seg * 16;
        f16x8 t[2];
#pragma unroll
        for (int hf = 0; hf < 2; ++hf) {
            f32x4 a = *(const f32x4*)(kp + hf * 8);
            f32x4 c = *(const f32x4*)(kp + hf * 8 + 4);
#pragma unroll
            for (int i = 0; i < 8; ++i) t[hf][i] = (_Float16)((i < 4) ? a[i] : c[i - 4]);
        }
        const int x = (kk & 7) << 4;
        *(f16x8*)(tile + kk * 128 + ((seg * 32) ^ x))      = t[0];
        *(f16x8*)(tile + kk * 128 + ((seg * 32 + 16) ^ x)) = t[1];
    }
    {   // V^T: thread -> dh row d, key segment ks*16
        const int d = tid & 63, ks = tid >> 6;
        const float* vp = V + ((size_t)b * Ssz + kt * 64 + ks * 16) * Esz + h * DHsz + d;
        f16x8 t[2];
#pragma unroll
        for (int j = 0; j < 16; ++j)
            t[j >> 3][j & 7] = (_Float16)vp[(size_t)j * Esz];
        const int x = (d & 7) << 4;
        *(f16x8*)(tile + 8192 + d * 128 + ((ks * 32) ^ x))      = t[0];
        *(f16x8*)(tile + 8192 + d * 128 + ((ks * 32 + 16) ^ x)) = t[1];
    }
    if (tid < 64)
        *(float*)(tile + 16384 + tid * 4) =
            mask[(size_t)b * Ssz + kt * 64 + tid] ? 0.0f : 1.0f;
}

__global__ __launch_bounds__(256) void prep_w(
    const float* __restrict__ W, char* __restrict__ Wt)
{
    const int kt = blockIdx.x, nt = blockIdx.y;
    char* tile = Wt + (size_t)(nt * 16 + kt) * 8192;
    const int n = threadIdx.x >> 2, seg = threadIdx.x & 3;
    const float* wp = W + (size_t)(nt * 64 + n) * Esz + kt * 64 + seg * 16;
    f16x8 t[2];
#pragma unroll
    for (int hf = 0; hf < 2; ++hf) {
        f32x4 a = *(const f32x4*)(wp + hf * 8);
        f32x4 c = *(const f32x4*)(wp + hf * 8 + 4);
#pragma unroll
        for (int i = 0; i < 8; ++i) t[hf][i] = (_Float16)((i < 4) ? a[i] : c[i - 4]);
    }
    const int x = (n & 7) << 4;
    *(f16x8*)(tile + n * 128 + ((seg * 32) ^ x))      = t[0];
    *(f16x8*)(tile + n * 128 + ((seg * 32 + 16) ^ x)) = t[1];
}

// ---------- fused attention: 128 queries/block, dbuf global_load_lds ----------
static __device__ __forceinline__ void stage(char* buf, const char* tile, int wid, int lane) {
#pragma unroll
    for (int i = 0; i < 4; ++i) {
        const int c = wid * 4 + i;
        gl_lds16(tile + c * 1024 + lane * 16, buf + c * 1024);
    }
    if (wid == 0)
        gl_lds4(tile + 16384 + lane * 4, buf + 16384);
}

__global__ __launch_bounds__(256, 3) void attn_kernel(
    const char* __restrict__ KVt, const float* __restrict__ Q,
    const float* __restrict__ scale_p, const float* __restrict__ logC_p,
    _Float16* __restrict__ X)
{
    __shared__ __align__(16) char     kvb[2][TILE_B];
    __shared__ __align__(16) _Float16 p_s[4][2048];   // per-wave P[32q][64k]

    const int tid = threadIdx.x;
    const int l   = tid & 63;
    const int wid = tid >> 6;
    const int l15 = l & 15;
    const int l4  = l >> 4;
    const int qt = blockIdx.x, h = blockIdx.y, b = blockIdx.z;

    const float LOG2E = 1.4426950408889634f;
    const float scale = scale_p[0];
    const float C     = __expf(logC_p[0]);
    const float k1l2  = scale * 0.25f * LOG2E;   // z = 2^(s*k1l2) = e^{2u}
    const float negl2 = -2.0f * C * LOG2E;       // p = 2^(negl2/(z+1))  (e^C dropped: cancels)

    const char* tiles = KVt + (size_t)((b * Hsz + h) * NKT) * TILE_B;

    // Q fragments fp16, 2 groups of 16 queries per wave
    f16x8 qf[2][2];
#pragma unroll
    for (int g = 0; g < 2; ++g) {
        const int qrow = qt * 128 + wid * 32 + g * 16 + l15;
        const float* qp = Q + ((size_t)b * Ssz + qrow) * Esz + h * DHsz + l4 * 8;
#pragma unroll
        for (int c = 0; c < 2; ++c) {
            f32x4 v0 = *(const f32x4*)(qp + 32 * c);
            f32x4 v1 = *(const f32x4*)(qp + 32 * c + 4);
#pragma unroll
            for (int i = 0; i < 8; ++i)
                qf[g][c][i] = (_Float16)((i < 4) ? v0[i] : v1[i - 4]);
        }
    }

    // ones B-fragment for the denominator MFMA: col 0 only
    const _Float16 ov = (l15 == 0) ? (_Float16)1.0f : (_Float16)0.0f;
    const f16x8 vb1 = {ov, ov, ov, ov, ov, ov, ov, ov};

    const f32x4 fzero = {0.f, 0.f, 0.f, 0.f};
    f32x4 oacc[2][4], dacc[2];
#pragma unroll
    for (int g = 0; g < 2; ++g) {
        dacc[g] = fzero;
#pragma unroll
        for (int st = 0; st < 4; ++st) oacc[g][st] = fzero;
    }
    char* pb = (char*)&p_s[wid][0];

    stage(kvb[0], tiles, wid, l);
    int cur = 0;
    for (int kt = 0; kt < NKT; ++kt) {
        __syncthreads();                      // buf[cur] staged; prev compute done
        if (kt < NKT - 1)
            stage(kvb[cur ^ 1], tiles + (size_t)(kt + 1) * TILE_B, wid, l);

        char* khb = kvb[cur];
        char* vtb = khb + 8192;
        const float* mkb = (const float*)(khb + 16384);

        // ---- QK^T (K frags read once, feed both query groups) + softmax
#pragma unroll
        for (int st = 0; st < 4; ++st) {
            f16x8 ka[2];
#pragma unroll
            for (int c = 0; c < 2; ++c)
                ka[c] = *(const f16x8*)swz(khb, st * 16 + l15, c * 64 + l4 * 16);
            f32x4 mkv = *(const f32x4*)(mkb + st * 16 + l4 * 4);
#pragma unroll
            for (int g = 0; g < 2; ++g) {
                __builtin_amdgcn_s_setprio(1);
                f32x4 sacc = fzero;
                sacc = mfma16h(ka[0], qf[g][0], sacc);
                sacc = mfma16h(ka[1], qf[g][1], sacc);
                __builtin_amdgcn_s_setprio(0);
                f16x4 pv4;
#pragma unroll
                for (int r = 0; r < 4; ++r) {
                    float z = fexp2(sacc[r] * k1l2);
                    float p = fexp2(negl2 * frcp(z + 1.0f)) * mkv[r];
                    pv4[r] = (_Float16)p;
                }
                *(f16x4*)swz(pb, g * 16 + l15, (st * 16 + l4 * 4) * 2) = pv4;
            }
        }

        // ---- PV + denominator: V frags read once, feed both groups
#pragma unroll
        for (int c = 0; c < 2; ++c) {
            f16x8 pa0 = *(const f16x8*)swz(pb, l15,      c * 64 + l4 * 16);
            f16x8 pa1 = *(const f16x8*)swz(pb, 16 + l15, c * 64 + l4 * 16);
            __builtin_amdgcn_s_setprio(1);
            dacc[0] = mfma16h(pa0, vb1, dacc[0]);
            dacc[1] = mfma16h(pa1, vb1, dacc[1]);
#pragma unroll
            for (int st = 0; st < 4; ++st) {
                f16x8 vb = *(const f16x8*)swz(vtb, st * 16 + l15, c * 64 + l4 * 16);
                oacc[0][st] = mfma16h(pa0, vb, oacc[0][st]);
                oacc[1][st] = mfma16h(pa1, vb, oacc[1][st]);
            }
            __builtin_amdgcn_s_setprio(0);
        }
        cur ^= 1;
    }

    // ---- epilogue: dsum for query l4*4+r lives in lane l4*16 (col 0), reg r
#pragma unroll
    for (int g = 0; g < 2; ++g) {
        float dd[4];
#pragma unroll
        for (int r = 0; r < 4; ++r)
            dd[r] = frcp(__shfl(dacc[g][r], l4 * 16, 64));
#pragma unroll
        for (int st = 0; st < 4; ++st)
#pragma unroll
            for (int r = 0; r < 4; ++r) {
                int row = qt * 128 + wid * 32 + g * 16 + l4 * 4 + r;
                X[((size_t)b * Ssz + row) * Esz + h * DHsz + st * 16 + l15] =
                    (_Float16)(oacc[g][st][r] * dd[r]);
            }
    }
}

// ---------- out = X(fp16) @ W^T (prepped fp16 tiles), fp32 out ----------
__global__ __launch_bounds__(256) void out_gemm(
    const _Float16* __restrict__ X, const char* __restrict__ Wt,
    float* __restrict__ out)
{
    __shared__ __align__(16) _Float16 xs[4096];
    __shared__ __align__(16) _Float16 wt[4096];
    char* xsb = (char*)xs;
    char* wtb = (char*)wt;

    const int tid = threadIdx.x;
    const int l   = tid & 63;
    const int wid = tid >> 6;
    const int l15 = l & 15;
    const int l4  = l >> 4;
    const int mbase = blockIdx.x * 64;
    const int nt    = blockIdx.y;

    const f32x4 fzero = {0.f, 0.f, 0.f, 0.f};
    f32x4 acc[4];
#pragma unroll
    for (int st = 0; st < 4; ++st) acc[st] = fzero;

    for (int kt = 0; kt < Esz / 64; ++kt) {
        __syncthreads();
        {   // W tile: direct global->LDS (pre-swizzled image)
            const char* wtile = Wt + (size_t)(nt * 16 + kt) * 8192;
#pragma unroll
            for (int i = 0; i < 2; ++i) {
                const int c = wid * 2 + i;
                gl_lds16(wtile + c * 1024 + l * 16, wtb + c * 1024);
            }
        }
        // X tile: reg path with swizzled writes
        for (int i = tid; i < 64 * 8; i += 256) {
            int r = i >> 3, c8 = i & 7;
            *(f16x8*)swz(xsb, r, c8 * 16) =
                *(const f16x8*)(X + (size_t)(mbase + r) * Esz + kt * 64 + c8 * 8);
        }
        __syncthreads();

        f16x8 a0 = *(const f16x8*)swz(xsb, wid * 16 + l15, l4 * 16);
        f16x8 a1 = *(const f16x8*)swz(xsb, wid * 16 + l15, 64 + l4 * 16);
#pragma unroll
        for (int st = 0; st < 4; ++st) {
            f16x8 b0 = *(const f16x8*)swz(wtb, st * 16 + l15, l4 * 16);
            f16x8 b1 = *(const f16x8*)swz(wtb, st * 16 + l15, 64 + l4 * 16);
            acc[st] = mfma16h(a0, b0, acc[st]);
            acc[st] = mfma16h(a1, b1, acc[st]);
        }
    }

#pragma unroll
    for (int st = 0; st < 4; ++st)
#pragma unroll
        for (int r = 0; r < 4; ++r)
            out[(size_t)(mbase + wid * 16 + l4 * 4 + r) * Esz + nt * 64 + st * 16 + l15] = acc[st][r];
}

extern "C" void kernel_launch(void* const* d_in, const int* in_sizes, int n_in,
                              void* d_out, int out_size, void* d_ws, size_t ws_size,
                              hipStream_t stream) {
    const float* Q     = (const float*)d_in[0];
    const float* K     = (const float*)d_in[1];
    const float* V     = (const float*)d_in[2];
    const int*   mask  = (const int*)d_in[3];
    const float* W     = (const float*)d_in[4];
    const float* scale = (const float*)d_in[5];
    const float* logC  = (const float*)d_in[6];

    char*     ws  = (char*)d_ws;          // needs ~53 MB scratch
    char*     KVt = ws;
    char*     Wt  = ws + WT_OFF;
    _Float16* X   = (_Float16*)(ws + X_OFF);
    float*    out = (float*)d_out;

    prep_kv<<<dim3(NKT, Hsz, Bsz), 256, 0, stream>>>(K, V, mask, KVt);
    prep_w<<<dim3(16, 16), 256, 0, stream>>>(W, Wt);
    attn_kernel<<<dim3(Ssz / 128, Hsz, Bsz), 256, 0, stream>>>(KVt, Q, scale, logC, X);
    out_gemm<<<dim3((Bsz * Ssz) / 64, Esz / 64), 256, 0, stream>>>(X, Wt, out);
}

// Round 7
// 192.459 us; speedup vs baseline: 2.1572x; 1.0509x over previous
//
#include <hip/hip_runtime.h>
#include <hip/hip_bf16.h>

#define Bsz 4
#define Ssz 2048
#define Esz 1024
#define Hsz 16
#define DHsz 64

// KV tile image (fp16): k 8KB | vt 8KB | mask(f32) 256B   per (b,h,kt64)
#define TILE_B 16640
#define NKT    (Ssz / 64)                    // 32 key tiles
#define WT_OFF  34078720                     // 256 W tiles x 8KB = 2MB
#define X_OFF   36175872                     // fp16 X, 16MB

typedef _Float16 f16x8 __attribute__((ext_vector_type(8)));
typedef _Float16 f16x4 __attribute__((ext_vector_type(4)));
typedef float    f32x4  __attribute__((ext_vector_type(4)));
typedef float    f32x16 __attribute__((ext_vector_type(16)));
typedef unsigned int u32;
typedef u32 u32x2 __attribute__((ext_vector_type(2)));
typedef u32 u32x4 __attribute__((ext_vector_type(4)));

static __device__ __forceinline__ f32x16 mfma32(f16x8 a, f16x8 b, f32x16 c) {
    return __builtin_amdgcn_mfma_f32_32x32x16_f16(a, b, c, 0, 0, 0);
}
static __device__ __forceinline__ f32x4 mfma16h(f16x8 a, f16x8 b, f32x4 c) {
    return __builtin_amdgcn_mfma_f32_16x16x32_f16(a, b, c, 0, 0, 0);
}

// Explicit drain: guarantees all global_load_lds writes + LDS ops are complete
// BEFORE the barrier, independent of compiler waitcnt placement (rule #18).
static __device__ __forceinline__ void drain_barrier() {
    asm volatile("s_waitcnt vmcnt(0) lgkmcnt(0)" ::: "memory");
    __builtin_amdgcn_sched_barrier(0);
    __syncthreads();
}

// Swizzled tile addressing: linear 128B rows, 16B slot XOR'd with (row&7).
static __device__ __forceinline__ char* swz(char* base, int row, int colByte) {
    return base + row * 128 + (colByte ^ ((row & 7) << 4));
}

typedef const unsigned int __attribute__((address_space(1))) as1_u32;
typedef unsigned int __attribute__((address_space(3))) as3_u32;
static __device__ __forceinline__ void gl_lds16(const void* g, void* l) {
    __builtin_amdgcn_global_load_lds((as1_u32*)g, (as3_u32*)l, 16, 0, 0);
}
static __device__ __forceinline__ void gl_lds4(const void* g, void* l) {
    __builtin_amdgcn_global_load_lds((as1_u32*)g, (as3_u32*)l, 4, 0, 0);
}

static __device__ __forceinline__ float fexp2(float x) {
#if __has_builtin(__builtin_amdgcn_exp2f)
    return __builtin_amdgcn_exp2f(x);
#else
    return __expf(x * 0.6931471805599453f);
#endif
}
static __device__ __forceinline__ float frcp(float x) {
#if __has_builtin(__builtin_amdgcn_rcpf)
    return __builtin_amdgcn_rcpf(x);
#else
    return __fdividef(1.0f, x);
#endif
}

// ---------- prepass: K->fp16, V->V^T fp16, mask->additive-log f32 ----------
__global__ __launch_bounds__(256) void prep_kv(
    const float* __restrict__ K, const float* __restrict__ V,
    const int* __restrict__ mask, char* __restrict__ KVt)
{
    const int kt = blockIdx.x, h = blockIdx.y, b = blockIdx.z;
    char* tile = KVt + (size_t)((b * Hsz + h) * NKT + kt) * TILE_B;
    const int tid = threadIdx.x;

    {   // K: thread -> row kk, d-segment seg*16
        const int kk = tid >> 2, seg = tid & 3;
        const float* kp = K + ((size_t)b * Ssz + kt * 64 + kk) * Esz + h * DHsz + seg * 16;
        f16x8 t[2];
#pragma unroll
        for (int hf = 0; hf < 2; ++hf) {
            f32x4 a = *(const f32x4*)(kp + hf * 8);
            f32x4 c = *(const f32x4*)(kp + hf * 8 + 4);
#pragma unroll
            for (int i = 0; i < 8; ++i) t[hf][i] = (_Float16)((i < 4) ? a[i] : c[i - 4]);
        }
        const int x = (kk & 7) << 4;
        *(f16x8*)(tile + kk * 128 + ((seg * 32) ^ x))      = t[0];
        *(f16x8*)(tile + kk * 128 + ((seg * 32 + 16) ^ x)) = t[1];
    }
    {   // V^T: thread -> dh row d, key segment ks*16
        const int d = tid & 63, ks = tid >> 6;
        const float* vp = V + ((size_t)b * Ssz + kt * 64 + ks * 16) * Esz + h * DHsz + d;
        f16x8 t[2];
#pragma unroll
        for (int j = 0; j < 16; ++j)
            t[j >> 3][j & 7] = (_Float16)vp[(size_t)j * Esz];
        const int x = (d & 7) << 4;
        *(f16x8*)(tile + 8192 + d * 128 + ((ks * 32) ^ x))      = t[0];
        *(f16x8*)(tile + 8192 + d * 128 + ((ks * 32 + 16) ^ x)) = t[1];
    }
    if (tid < 64)
        *(float*)(tile + 16384 + tid * 4) =
            mask[(size_t)b * Ssz + kt * 64 + tid] ? -100000.0f : 0.0f;
}

__global__ __launch_bounds__(256) void prep_w(
    const float* __restrict__ W, char* __restrict__ Wt)
{
    const int kt = blockIdx.x, nt = blockIdx.y;
    char* tile = Wt + (size_t)(nt * 16 + kt) * 8192;
    const int n = threadIdx.x >> 2, seg = threadIdx.x & 3;
    const float* wp = W + (size_t)(nt * 64 + n) * Esz + kt * 64 + seg * 16;
    f16x8 t[2];
#pragma unroll
    for (int hf = 0; hf < 2; ++hf) {
        f32x4 a = *(const f32x4*)(wp + hf * 8);
        f32x4 c = *(const f32x4*)(wp + hf * 8 + 4);
#pragma unroll
        for (int i = 0; i < 8; ++i) t[hf][i] = (_Float16)((i < 4) ? a[i] : c[i - 4]);
    }
    const int x = (n & 7) << 4;
    *(f16x8*)(tile + n * 128 + ((seg * 32) ^ x))      = t[0];
    *(f16x8*)(tile + n * 128 + ((seg * 32 + 16) ^ x)) = t[1];
}

// ---------- fused attention: 128 q/block, 32x32 MFMA, P in registers ----------
static __device__ __forceinline__ void stage(char* buf, const char* tile, int wid, int lane) {
#pragma unroll
    for (int i = 0; i < 4; ++i) {
        const int c = wid * 4 + i;
        gl_lds16(tile + c * 1024 + lane * 16, buf + c * 1024);
    }
    if (wid == 0)
        gl_lds4(tile + 16384 + lane * 4, buf + 16384);
}

__global__ __launch_bounds__(256, 4) void attn_kernel(
    const char* __restrict__ KVt, const float* __restrict__ Q,
    const float* __restrict__ scale_p, const float* __restrict__ logC_p,
    _Float16* __restrict__ X)
{
    __shared__ __align__(16) char kvb[2][TILE_B];

    const int tid = threadIdx.x;
    const int l   = tid & 63;
    const int wid = tid >> 6;
    const int q32 = l & 31;     // query column
    const int hi  = l >> 5;     // lane half

    // XCD-chunked swizzle: all 16 q-blocks of one (b,h) -> same XCD
    const int orig = blockIdx.x;
    const int work = (orig & 7) * 128 + (orig >> 3);
    const int bh = work >> 4, qt = work & 15;
    const int b = bh >> 4, h = bh & 15;

    const float LOG2E = 1.4426950408889634f;
    const float scale = scale_p[0];
    const float C     = __expf(logC_p[0]);
    const float k1l2  = scale * 0.25f * LOG2E;   // z = 2^(s*k1l2) = e^{2u}
    const float negl2 = -2.0f * C * LOG2E;       // p = 2^(negl2/(z+1) + masklog)

    const char* tiles = KVt + (size_t)bh * NKT * TILE_B;
    const int qbase = qt * 128 + wid * 32;

    // Q fragments: qf[ch][j] = Q[qbase+q32][ch*16 + hi*8 + j]
    f16x8 qf[4];
    {
        const float* qp = Q + ((size_t)b * Ssz + qbase + q32) * Esz + h * DHsz + hi * 8;
#pragma unroll
        for (int ch = 0; ch < 4; ++ch) {
            f32x4 v0 = *(const f32x4*)(qp + ch * 16);
            f32x4 v1 = *(const f32x4*)(qp + ch * 16 + 4);
#pragma unroll
            for (int i = 0; i < 8; ++i)
                qf[ch][i] = (_Float16)((i < 4) ? v0[i] : v1[i - 4]);
        }
    }

    f32x16 oaccT[2];
#pragma unroll
    for (int t = 0; t < 2; ++t)
#pragma unroll
        for (int r = 0; r < 16; ++r) oaccT[t][r] = 0.0f;
    float dsum = 0.0f;

    stage(kvb[0], tiles, wid, l);
    int cur = 0;
    for (int kt = 0; kt < NKT; ++kt) {
        drain_barrier();                       // buf[cur] fully staged for ALL waves
        if (kt < NKT - 1)
            stage(kvb[cur ^ 1], tiles + (size_t)(kt + 1) * TILE_B, wid, l);

        char* kb  = kvb[cur];
        char* vtb = kb + 8192;
        const char* mkb = kb + 16384;

#pragma unroll
        for (int ktile = 0; ktile < 2; ++ktile) {
            // ---- QK^T (swapped): D[key][query]; key = ktile*32 + i + 8*rg + 4*hi
            f32x16 sacc;
#pragma unroll
            for (int r = 0; r < 16; ++r) sacc[r] = 0.0f;
            __builtin_amdgcn_s_setprio(1);
#pragma unroll
            for (int ch = 0; ch < 4; ++ch) {
                f16x8 ka = *(const f16x8*)swz(kb, ktile * 32 + q32, ch * 32 + hi * 16);
                sacc = mfma32(ka, qf[ch], sacc);
            }
            __builtin_amdgcn_s_setprio(0);

            // ---- softmax + pack to f16 pairs (keys 8*rg + 4*hi + {0..3} per rg)
            u32 ownA[4], ownB[4], gotA[4], gotB[4];
#pragma unroll
            for (int rg = 0; rg < 4; ++rg) {
                f32x4 mk = *(const f32x4*)(mkb + ((ktile * 8 + 2 * rg + hi) << 4));
                float p0, p1, p2, p3;
                {
                    float z0 = fexp2(sacc[rg * 4 + 0] * k1l2);
                    float z1 = fexp2(sacc[rg * 4 + 1] * k1l2);
                    float z2 = fexp2(sacc[rg * 4 + 2] * k1l2);
                    float z3 = fexp2(sacc[rg * 4 + 3] * k1l2);
                    p0 = fexp2(fmaf(negl2, frcp(z0 + 1.f), mk[0]));
                    p1 = fexp2(fmaf(negl2, frcp(z1 + 1.f), mk[1]));
                    p2 = fexp2(fmaf(negl2, frcp(z2 + 1.f), mk[2]));
                    p3 = fexp2(fmaf(negl2, frcp(z3 + 1.f), mk[3]));
                }
                dsum += (p0 + p1) + (p2 + p3);
                ownA[rg] = __builtin_bit_cast(u32, __builtin_amdgcn_cvt_pkrtz(p0, p1));
                ownB[rg] = __builtin_bit_cast(u32, __builtin_amdgcn_cvt_pkrtz(p2, p3));
            }
#pragma unroll
            for (int rg = 0; rg < 4; ++rg) {
                gotA[rg] = (u32)__shfl_xor((int)ownA[rg], 32, 64);
                gotB[rg] = (u32)__shfl_xor((int)ownB[rg], 32, 64);
            }

            // ---- PV (O^T): B-frag = P[key-chunk][query], A = V^T
#pragma unroll
            for (int c = 0; c < 2; ++c) {
                u32x4 pw;
                pw[0] = hi ? gotA[2 * c + 1] : ownA[2 * c];
                pw[1] = hi ? gotB[2 * c + 1] : ownB[2 * c];
                pw[2] = hi ? ownA[2 * c + 1] : gotA[2 * c];
                pw[3] = hi ? ownB[2 * c + 1] : gotB[2 * c];
                f16x8 pf = __builtin_bit_cast(f16x8, pw);
                const int kc = ktile * 2 + c;
                __builtin_amdgcn_s_setprio(1);
#pragma unroll
                for (int t = 0; t < 2; ++t) {
                    f16x8 va = *(const f16x8*)swz(vtb, t * 32 + q32, kc * 32 + hi * 16);
                    oaccT[t] = mfma32(va, pf, oaccT[t]);
                }
                __builtin_amdgcn_s_setprio(0);
            }
        }
        cur ^= 1;
    }

    // ---- epilogue: denominator + O^T store (row = query, packed f16x4)
    dsum += __shfl_xor(dsum, 32, 64);
    const float dd = frcp(dsum);
    _Float16* xp = X + ((size_t)b * Ssz + qbase + q32) * Esz + h * DHsz + hi * 4;
#pragma unroll
    for (int t = 0; t < 2; ++t)
#pragma unroll
        for (int rg = 0; rg < 4; ++rg) {
            u32x2 w;
            w[0] = __builtin_bit_cast(u32, __builtin_amdgcn_cvt_pkrtz(
                       oaccT[t][rg * 4 + 0] * dd, oaccT[t][rg * 4 + 1] * dd));
            w[1] = __builtin_bit_cast(u32, __builtin_amdgcn_cvt_pkrtz(
                       oaccT[t][rg * 4 + 2] * dd, oaccT[t][rg * 4 + 3] * dd));
            *(u32x2*)(xp + t * 32 + rg * 8) = w;
        }
}

// ---------- out = X(fp16) @ W^T (prepped fp16 tiles), fp32 out ----------
__global__ __launch_bounds__(256) void out_gemm(
    const _Float16* __restrict__ X, const char* __restrict__ Wt,
    float* __restrict__ out)
{
    __shared__ __align__(16) _Float16 xs[4096];
    __shared__ __align__(16) _Float16 wt[4096];
    char* xsb = (char*)xs;
    char* wtb = (char*)wt;

    const int tid = threadIdx.x;
    const int l   = tid & 63;
    const int wid = tid >> 6;
    const int l15 = l & 15;
    const int l4  = l >> 4;
    const int mbase = blockIdx.x * 64;
    const int nt    = blockIdx.y;

    const f32x4 fzero = {0.f, 0.f, 0.f, 0.f};
    f32x4 acc[4];
#pragma unroll
    for (int st = 0; st < 4; ++st) acc[st] = fzero;

    for (int kt = 0; kt < Esz / 64; ++kt) {
        drain_barrier();
        {   // W tile: direct global->LDS (pre-swizzled image)
            const char* wtile = Wt + (size_t)(nt * 16 + kt) * 8192;
#pragma unroll
            for (int i = 0; i < 2; ++i) {
                const int c = wid * 2 + i;
                gl_lds16(wtile + c * 1024 + l * 16, wtb + c * 1024);
            }
        }
        // X tile: reg path with swizzled writes
        for (int i = tid; i < 64 * 8; i += 256) {
            int r = i >> 3, c8 = i & 7;
            *(f16x8*)swz(xsb, r, c8 * 16) =
                *(const f16x8*)(X + (size_t)(mbase + r) * Esz + kt * 64 + c8 * 8);
        }
        drain_barrier();

        f16x8 a0 = *(const f16x8*)swz(xsb, wid * 16 + l15, l4 * 16);
        f16x8 a1 = *(const f16x8*)swz(xsb, wid * 16 + l15, 64 + l4 * 16);
#pragma unroll
        for (int st = 0; st < 4; ++st) {
            f16x8 b0 = *(const f16x8*)swz(wtb, st * 16 + l15, l4 * 16);
            f16x8 b1 = *(const f16x8*)swz(wtb, st * 16 + l15, 64 + l4 * 16);
            acc[st] = mfma16h(a0, b0, acc[st]);
            acc[st] = mfma16h(a1, b1, acc[st]);
        }
    }

#pragma unroll
    for (int st = 0; st < 4; ++st)
#pragma unroll
        for (int r = 0; r < 4; ++r)
            out[(size_t)(mbase + wid * 16 + l4 * 4 + r) * Esz + nt * 64 + st * 16 + l15] = acc[st][r];
}

extern "C" void kernel_launch(void* const* d_in, const int* in_sizes, int n_in,
                              void* d_out, int out_size, void* d_ws, size_t ws_size,
                              hipStream_t stream) {
    const float* Q     = (const float*)d_in[0];
    const float* K     = (const float*)d_in[1];
    const float* V     = (const float*)d_in[2];
    const int*   mask  = (const int*)d_in[3];
    const float* W     = (const float*)d_in[4];
    const float* scale = (const float*)d_in[5];
    const float* logC  = (const float*)d_in[6];

    char*     ws  = (char*)d_ws;          // needs ~53 MB scratch
    char*     KVt = ws;
    char*     Wt  = ws + WT_OFF;
    _Float16* X   = (_Float16*)(ws + X_OFF);
    float*    out = (float*)d_out;

    prep_kv<<<dim3(NKT, Hsz, Bsz), 256, 0, stream>>>(K, V, mask, KVt);
    prep_w<<<dim3(16, 16), 256, 0, stream>>>(W, Wt);
    attn_kernel<<<1024, 256, 0, stream>>>(KVt, Q, scale, logC, X);
    out_gemm<<<dim3((Bsz * Ssz) / 64, Esz / 64), 256, 0, stream>>>(X, Wt, out);
}